// Round 8
// baseline (6638.235 us; speedup 1.0000x reference)
//
#include <hip/hip_runtime.h>
#include <math.h>

#define LOG2E 1.4426950408889634f
#define KQ 16   // max entries per column-quarter (column nnz <= 64)

// ---------------------------------------------------------------------------
// prep_csc: fixed-stride padded CSC [col][quarter(4)][KQ] of recurrent synapses.
// entry {p=-sigma*log2e, q=sigma*mu*log2e, s=softplus(w)*erev, w=i*4 (byte off)}.
// Zero-padded (p=q=s=0 -> sigmoid(0)=0.5, s*0.5=0: exact no-op).
// Column c-th nonzero -> quarter c&3. Within a quarter, entries sorted by
// ((i&31) - lane_slot)&31 so step-k banks across the wave rotate near-perfectly.
// meta: [0..127]=cnt by col, [128..255]=perm (rank-sorted desc by cnt).
// ---------------------------------------------------------------------------
__global__ __launch_bounds__(128)
void lnn_prep_csc(const float* __restrict__ sigma, const float* __restrict__ mu,
                  const float* __restrict__ w, const float* __restrict__ erev,
                  const float* __restrict__ mask,
                  float4* __restrict__ ent_g, int* __restrict__ meta_g)
{
    __shared__ int cnt_s[128], rank_s[128];
    const int j = threadIdx.x;
    int cnt = 0;
    for (int i = 0; i < 128; ++i) cnt += (mask[i * 128 + j] != 0.0f) ? 1 : 0;
    cnt_s[j] = cnt;
    __syncthreads();
    int rank = 0;
    for (int i = 0; i < 128; ++i) {
        int ci = cnt_s[i];
        rank += (ci > cnt || (ci == cnt && i < j)) ? 1 : 0;
    }
    meta_g[j] = cnt;
    meta_g[128 + rank] = j;
    rank_s[j] = rank;
    __syncthreads();
    const int slotbase = (rank_s[j] & 15) * 4;

    float4 z; z.x = 0.f; z.y = 0.f; z.z = 0.f; z.w = __int_as_float(0);
    for (int c = 0; c < 64; ++c) ent_g[(j << 6) + c] = z;

    for (int q = 0; q < 4; ++q) {
        int idxs[KQ];
        int m = 0, c = 0;
        for (int i = 0; i < 128; ++i) {
            if (mask[i * 128 + j] != 0.0f) {
                if ((c & 3) == q && m < KQ) idxs[m++] = i;
                ++c;
            }
        }
        const int slot = (slotbase + q) & 31;
        for (int a = 1; a < m; ++a) {            // insertion sort by bank key
            int v = idxs[a];
            int kv = ((v & 31) - slot) & 31;
            int bp = a;
            while (bp > 0) {
                int u = idxs[bp - 1];
                if ((((u & 31) - slot) & 31) <= kv) break;
                idxs[bp] = u; --bp;
            }
            idxs[bp] = v;
        }
        for (int k = 0; k < m; ++k) {
            int i = idxs[k];
            int gi = i * 128 + j;
            float sg = sigma[gi], mm = mu[gi];
            float4 e;
            e.x = -sg * LOG2E;
            e.y = sg * mm * LOG2E;
            e.z = log1pf(expf(w[gi])) * erev[gi];
            e.w = __int_as_float(i << 2);        // byte offset into vb
            ent_g[(j << 6) + (q << 4) + k] = e;
        }
    }
}

// ---------------------------------------------------------------------------
// prep_sens: sensory synapse constants (6x128).
// ---------------------------------------------------------------------------
__global__ __launch_bounds__(768)
void lnn_prep_sens(const float* __restrict__ ssig, const float* __restrict__ smu,
                   const float* __restrict__ sw, const float* __restrict__ serev,
                   const float* __restrict__ smask,
                   float* __restrict__ g_sp, float* __restrict__ g_sq,
                   float* __restrict__ g_ss)
{
    int idx = threadIdx.x;
    float sg = ssig[idx], m = smu[idx];
    g_sp[idx] = -sg * LOG2E;
    g_sq[idx] = sg * m * LOG2E;
    g_ss[idx] = log1pf(expf(sw[idx])) * smask[idx] * serev[idx];
}

// ---------------------------------------------------------------------------
// prep2: LayerNorm(6) + input affine folded -> inp [B*T][6].
// ---------------------------------------------------------------------------
__global__ void lnn_prep2(const float* __restrict__ x,
                          const float* __restrict__ ln_g, const float* __restrict__ ln_b,
                          const float* __restrict__ in_w, const float* __restrict__ in_b,
                          float* __restrict__ inp)
{
    int r = blockIdx.x * 256 + threadIdx.x;
    if (r >= 1024 * 96) return;
    const float* xp = x + r * 6;
    float v[6];
#pragma unroll
    for (int k = 0; k < 6; ++k) v[k] = xp[k];
    float m = (v[0] + v[1] + v[2] + v[3] + v[4] + v[5]) * (1.0f / 6.0f);
    float var = 0.f;
#pragma unroll
    for (int k = 0; k < 6; ++k) { float d = v[k] - m; var = fmaf(d, d, var); }
    var *= (1.0f / 6.0f);
    float rs = rsqrtf(var + 1e-5f);
    float* op = inp + r * 6;
#pragma unroll
    for (int k = 0; k < 6; ++k)
        op[k] = fmaf(fmaf((v[k] - m) * rs, ln_g[k], ln_b[k]), in_w[k], in_b[k]);
}

// ---------------------------------------------------------------------------
// main (sparse, reg-entries): 1024 blocks x 512 threads; block = 1 batch elem.
// thread: j_slot = tid>>2 (rank), q = tid&3 (quarter). jj = perm[j_slot].
// Entries in 64 VGPRs (16 x float4), zero-padded; k-loop runs to wave-uniform
// kqmax (scalar break, static reg indices). Only LDS in the loop: vb gather,
// bank-matched by prep's sort. 2 blocks/CU hide barrier tails.
// ---------------------------------------------------------------------------
__global__ __launch_bounds__(512, 4)
void lnn_main_sp(const float* __restrict__ inp, const float4* __restrict__ ent_g,
                 const int* __restrict__ meta_g,
                 const float* __restrict__ g_sp, const float* __restrict__ g_sq,
                 const float* __restrict__ g_ss,
                 const float* __restrict__ g_gleak, const float* __restrict__ g_vleak,
                 const float* __restrict__ g_cm,
                 const float* __restrict__ g_ow, const float* __restrict__ g_ob,
                 float* __restrict__ outs)
{
    __shared__ float vb[128];
    __shared__ float sp_s[768], sq_s[768], ss_s[768];
    __shared__ float cmt_s[128], gl_s[128], glvl_s[128];
    __shared__ float ow_s[64], ob_s[64];

    const int tid = threadIdx.x;
    const int j_slot = tid >> 2;
    const int q = tid & 3;
    const int jj = meta_g[128 + j_slot];
    const int cnt = meta_g[jj];
    const int kq_lane = (cnt + 3 - q) >> 2;

    if (tid < 128) vb[tid] = 0.f;
    for (int idx = tid; idx < 768; idx += 512) {
        sp_s[idx] = g_sp[idx]; sq_s[idx] = g_sq[idx]; ss_s[idx] = g_ss[idx];
    }
    if (tid < 128) {
        cmt_s[tid] = log1pf(expf(g_cm[tid])) * 6.0f;
        float gl = log1pf(expf(g_gleak[tid]));
        gl_s[tid] = gl;
        glvl_s[tid] = gl * g_vleak[tid];
    }
    if (tid < 64) { ow_s[tid] = g_ow[tid]; ob_s[tid] = g_ob[tid]; }

    // entries -> registers (zero-padded to KQ)
    float4 e[KQ];
    const float4* eg = ent_g + (((jj << 2) + q) << 4);
#pragma unroll
    for (int k = 0; k < KQ; ++k) e[k] = eg[k];

    // wave-uniform trip count
    int kqm = kq_lane;
#pragma unroll
    for (int m = 1; m < 64; m <<= 1) kqm = max(kqm, __shfl_xor(kqm, m));
    kqm = __builtin_amdgcn_readfirstlane(kqm);

    __syncthreads();

    const float cmt = cmt_s[jj], glf = gl_s[jj], glvl = glvl_s[jj];
    const float osc = (jj < 64) ? ow_s[jj] : 0.f;
    const float obi = (jj < 64) ? ob_s[jj] : 0.f;
    const int bg = blockIdx.x;
    const float* iprow = inp + bg * 576;
    float* orow = outs + ((bg * 96) << 6) + jj;
    float vcur = 0.f;
    const char* vbc = (const char*)vb;

    for (int t = 0; t < 96; ++t) {
        // sensory: q handles k=q (all) and k=q+4 (q<2) -> covers k=0..5
        float sn, sd;
        {
            const int k1 = q;
            float z = fmaf(sp_s[(k1 << 7) + jj], iprow[k1], sq_s[(k1 << 7) + jj]);
            float r = __builtin_amdgcn_rcpf(1.0f + __builtin_amdgcn_exp2f(z));
            float sv = ss_s[(k1 << 7) + jj];
            sn = sv * r;
            sd = fabsf(sv) * r;
            if (q < 2) {
                const int k2 = q + 4;
                float z2 = fmaf(sp_s[(k2 << 7) + jj], iprow[k2], sq_s[(k2 << 7) + jj]);
                float r2 = __builtin_amdgcn_rcpf(1.0f + __builtin_amdgcn_exp2f(z2));
                float sv2 = ss_s[(k2 << 7) + jj];
                sn = fmaf(sv2, r2, sn);
                sd = fmaf(fabsf(sv2), r2, sd);
            }
        }
        sn += __shfl_xor(sn, 1); sd += __shfl_xor(sd, 1);
        sn += __shfl_xor(sn, 2); sd += __shfl_xor(sd, 2);
        iprow += 6;

        for (int u = 0; u < 6; ++u) {
            float n = 0.f, d = 0.f;
#pragma unroll
            for (int k = 0; k < KQ; ++k) {
                if (k >= kqm) break;   // scalar (wave-uniform) break
                float v = *(const float*)(vbc + __float_as_int(e[k].w));
                float z = fmaf(e[k].x, v, e[k].y);
                float r = __builtin_amdgcn_rcpf(1.0f + __builtin_amdgcn_exp2f(z));
                n = fmaf(e[k].z, r, n);
                d = fmaf(fabsf(e[k].z), r, d);
            }
            n += __shfl_xor(n, 1); d += __shfl_xor(d, 1);
            n += __shfl_xor(n, 2); d += __shfl_xor(d, 2);
            __syncthreads();   // all vb reads done before update writes
            float num = fmaf(cmt, vcur, glvl) + n + sn;
            float den = cmt + glf + d + sd;
            vcur = num / (den + 1e-8f);
            if (q == 0) {
                vb[jj] = vcur;
                if (u == 5 && jj < 64) orow[0] = fmaf(vcur, osc, obi);
            }
            __syncthreads();   // updates visible to next unfold
        }
        orow += 64;
    }
}

// ---------------------------------------------------------------------------
// attention pooling over T + classifier, one block per batch element.
// ---------------------------------------------------------------------------
__global__ __launch_bounds__(128)
void lnn_attn(const float* __restrict__ outs,
              const float* __restrict__ aw1, const float* __restrict__ ab1,
              const float* __restrict__ aw2,
              const float* __restrict__ cw1, const float* __restrict__ cb1,
              const float* __restrict__ cw2, const float* __restrict__ cb2,
              float* __restrict__ out)
{
    __shared__ float o_s[96 * 65];
    __shared__ float aw1_s[64 * 32];
    __shared__ float scr[96], attw[96], ctx_s[64], h2_s[128];

    const int b = blockIdx.x, tid = threadIdx.x;
    const float* ob = outs + b * 6144;
    for (int idx = tid; idx < 6144; idx += 128)
        o_s[(idx >> 6) * 65 + (idx & 63)] = ob[idx];
    for (int idx = tid; idx < 2048; idx += 128)
        aw1_s[idx] = aw1[idx];
    __syncthreads();

    if (tid < 96) {
        float h1[32];
#pragma unroll
        for (int m = 0; m < 32; ++m) h1[m] = ab1[m];
        for (int jj = 0; jj < 64; ++jj) {
            float ov = o_s[tid * 65 + jj];
#pragma unroll
            for (int m = 0; m < 32; ++m) h1[m] = fmaf(ov, aw1_s[(jj << 5) + m], h1[m]);
        }
        float sc = 0.f;
#pragma unroll
        for (int m = 0; m < 32; ++m) sc = fmaf(fmaxf(h1[m], 0.f), aw2[m], sc);
        scr[tid] = sc;
    }
    __syncthreads();

    float mx = -1e30f;
    for (int k = 0; k < 96; ++k) mx = fmaxf(mx, scr[k]);
    float sum = 0.f;
    for (int k = 0; k < 96; ++k) sum += expf(scr[k] - mx);
    if (tid < 96) attw[tid] = expf(scr[tid] - mx) / sum;
    __syncthreads();

    if (tid < 64) {
        float c = 0.f;
        for (int k = 0; k < 96; ++k) c = fmaf(attw[k], o_s[k * 65 + tid], c);
        ctx_s[tid] = c;
    }
    __syncthreads();

    {
        float a = cb1[tid];
        for (int jj = 0; jj < 64; ++jj) a = fmaf(ctx_s[jj], cw1[(jj << 7) + tid], a);
        h2_s[tid] = fmaxf(a, 0.f);
    }
    __syncthreads();

    if (tid < 100) {
        float a = cb2[tid];
        for (int m = 0; m < 128; ++m) a = fmaf(h2_s[m], cw2[m * 100 + tid], a);
        out[b * 100 + tid] = a;
    }
}

// ---------------------------------------------------------------------------
extern "C" void kernel_launch(void* const* d_in, const int* in_sizes, int n_in,
                              void* d_out, int out_size, void* d_ws, size_t ws_size,
                              hipStream_t stream)
{
    const float* x     = (const float*)d_in[0];
    const float* ln_g  = (const float*)d_in[1];
    const float* ln_b  = (const float*)d_in[2];
    const float* gleak = (const float*)d_in[3];
    const float* vleak = (const float*)d_in[4];
    const float* cm    = (const float*)d_in[5];
    const float* sigma = (const float*)d_in[6];
    const float* mu    = (const float*)d_in[7];
    const float* w     = (const float*)d_in[8];
    const float* erev  = (const float*)d_in[9];
    const float* ssig  = (const float*)d_in[10];
    const float* smu   = (const float*)d_in[11];
    const float* sw    = (const float*)d_in[12];
    const float* serev = (const float*)d_in[13];
    const float* in_w  = (const float*)d_in[14];
    const float* in_b  = (const float*)d_in[15];
    const float* ow    = (const float*)d_in[16];
    const float* obb   = (const float*)d_in[17];
    const float* aw1   = (const float*)d_in[18];
    const float* ab1   = (const float*)d_in[19];
    const float* aw2   = (const float*)d_in[20];
    const float* cw1   = (const float*)d_in[21];
    const float* cb1   = (const float*)d_in[22];
    const float* cw2   = (const float*)d_in[23];
    const float* cb2   = (const float*)d_in[24];
    const float* mask  = (const float*)d_in[25];
    const float* smask = (const float*)d_in[26];

    float* ws = (float*)d_ws;
    float*  inp   = ws;                          // 589824 f
    float*  sp    = ws + 589824;                 // 768
    float*  sq    = ws + 590592;                 // 768
    float*  ss    = ws + 591360;                 // 768
    float4* ent_g = (float4*)(ws + 592128);      // 128*64 float4 = 32768 f (16B aligned)
    int*    meta  = (int*)(ws + 624896);         // 256 ints (pad 512)
    float*  outs  = ws + 625408;                 // 6291456 f

    lnn_prep_csc<<<1, 128, 0, stream>>>(sigma, mu, w, erev, mask, ent_g, meta);
    lnn_prep_sens<<<1, 768, 0, stream>>>(ssig, smu, sw, serev, smask, sp, sq, ss);
    lnn_prep2<<<384, 256, 0, stream>>>(x, ln_g, ln_b, in_w, in_b, inp);
    lnn_main_sp<<<1024, 512, 0, stream>>>(inp, ent_g, meta, sp, sq, ss,
                                          gleak, vleak, cm, ow, obb, outs);
    lnn_attn<<<1024, 128, 0, stream>>>(outs, aw1, ab1, aw2, cw1, cb1, cw2, cb2,
                                       (float*)d_out);
}

// Round 9
// 1479.932 us; speedup vs baseline: 4.4855x; 4.4855x over previous
//
#include <hip/hip_runtime.h>
#include <math.h>

#define LOG2E 1.4426950408889634f
#define KQ 16   // max entries per column-quarter (column nnz <= 64)

// ---------------------------------------------------------------------------
// prep_csc: fixed-stride padded CSC [col][quarter(4)][KQ] of recurrent synapses.
// entry {p=-sigma*log2e, q=sigma*mu*log2e, s=softplus(w)*erev, w=i*4 (byte off)}.
// Zero-padded (p=q=s=0 -> s*sigmoid(0)=0: exact no-op).
// Column c-th nonzero -> quarter c&3. Within a quarter, entries sorted by
// ((i&31) - lane_slot)&31 so step-k banks across the wave rotate near-perfectly.
// meta: [0..127]=cnt by col, [128..255]=perm (rank-sorted desc by cnt).
// ---------------------------------------------------------------------------
__global__ __launch_bounds__(128)
void lnn_prep_csc(const float* __restrict__ sigma, const float* __restrict__ mu,
                  const float* __restrict__ w, const float* __restrict__ erev,
                  const float* __restrict__ mask,
                  float4* __restrict__ ent_g, int* __restrict__ meta_g)
{
    __shared__ int cnt_s[128], rank_s[128];
    const int j = threadIdx.x;
    int cnt = 0;
    for (int i = 0; i < 128; ++i) cnt += (mask[i * 128 + j] != 0.0f) ? 1 : 0;
    cnt_s[j] = cnt;
    __syncthreads();
    int rank = 0;
    for (int i = 0; i < 128; ++i) {
        int ci = cnt_s[i];
        rank += (ci > cnt || (ci == cnt && i < j)) ? 1 : 0;
    }
    meta_g[j] = cnt;
    meta_g[128 + rank] = j;
    rank_s[j] = rank;
    __syncthreads();
    const int slotbase = (rank_s[j] & 15) * 4;

    float4 z; z.x = 0.f; z.y = 0.f; z.z = 0.f; z.w = __int_as_float(0);
    for (int c = 0; c < 64; ++c) ent_g[(j << 6) + c] = z;

    for (int q = 0; q < 4; ++q) {
        int idxs[KQ];
        int m = 0, c = 0;
        for (int i = 0; i < 128; ++i) {
            if (mask[i * 128 + j] != 0.0f) {
                if ((c & 3) == q && m < KQ) idxs[m++] = i;
                ++c;
            }
        }
        const int slot = (slotbase + q) & 31;
        for (int a = 1; a < m; ++a) {            // insertion sort by bank key
            int v = idxs[a];
            int kv = ((v & 31) - slot) & 31;
            int bp = a;
            while (bp > 0) {
                int u = idxs[bp - 1];
                if ((((u & 31) - slot) & 31) <= kv) break;
                idxs[bp] = u; --bp;
            }
            idxs[bp] = v;
        }
        for (int k = 0; k < m; ++k) {
            int i = idxs[k];
            int gi = i * 128 + j;
            float sg = sigma[gi], mm = mu[gi];
            float4 e;
            e.x = -sg * LOG2E;
            e.y = sg * mm * LOG2E;
            e.z = log1pf(expf(w[gi])) * erev[gi];
            e.w = __int_as_float(i << 2);        // byte offset into vb
            ent_g[(j << 6) + (q << 4) + k] = e;
        }
    }
}

// ---------------------------------------------------------------------------
// prep_sens: sensory synapse constants (6x128).
// ---------------------------------------------------------------------------
__global__ __launch_bounds__(768)
void lnn_prep_sens(const float* __restrict__ ssig, const float* __restrict__ smu,
                   const float* __restrict__ sw, const float* __restrict__ serev,
                   const float* __restrict__ smask,
                   float* __restrict__ g_sp, float* __restrict__ g_sq,
                   float* __restrict__ g_ss)
{
    int idx = threadIdx.x;
    float sg = ssig[idx], m = smu[idx];
    g_sp[idx] = -sg * LOG2E;
    g_sq[idx] = sg * m * LOG2E;
    g_ss[idx] = log1pf(expf(sw[idx])) * smask[idx] * serev[idx];
}

// ---------------------------------------------------------------------------
// prep2: LayerNorm(6) + input affine folded -> inp [B*T][6].
// ---------------------------------------------------------------------------
__global__ void lnn_prep2(const float* __restrict__ x,
                          const float* __restrict__ ln_g, const float* __restrict__ ln_b,
                          const float* __restrict__ in_w, const float* __restrict__ in_b,
                          float* __restrict__ inp)
{
    int r = blockIdx.x * 256 + threadIdx.x;
    if (r >= 1024 * 96) return;
    const float* xp = x + r * 6;
    float v[6];
#pragma unroll
    for (int k = 0; k < 6; ++k) v[k] = xp[k];
    float m = (v[0] + v[1] + v[2] + v[3] + v[4] + v[5]) * (1.0f / 6.0f);
    float var = 0.f;
#pragma unroll
    for (int k = 0; k < 6; ++k) { float d = v[k] - m; var = fmaf(d, d, var); }
    var *= (1.0f / 6.0f);
    float rs = rsqrtf(var + 1e-5f);
    float* op = inp + r * 6;
#pragma unroll
    for (int k = 0; k < 6; ++k)
        op[k] = fmaf(fmaf((v[k] - m) * rs, ln_g[k], ln_b[k]), in_w[k], in_b[k]);
}

// ---------------------------------------------------------------------------
// main (sparse, reg-entries): 1024 blocks x 512 threads; block = 1 batch elem.
// thread: j_slot = tid>>2 (rank), q = tid&3 (quarter). jj = perm[j_slot].
// Entries in 16 NAMED float4s, pinned into VGPRs via opaque asm (R8 lesson:
// an array + runtime break let the compiler rematerialize global loads inside
// the loop -> 19GB HBM traffic). k-loop fully unrolled, wave-uniform scalar
// guards. Only LDS in the loop: vb gather, bank-matched by prep's sort.
// ---------------------------------------------------------------------------
__global__ __launch_bounds__(512, 4)
void lnn_main_sp(const float* __restrict__ inp, const float4* __restrict__ ent_g,
                 const int* __restrict__ meta_g,
                 const float* __restrict__ g_sp, const float* __restrict__ g_sq,
                 const float* __restrict__ g_ss,
                 const float* __restrict__ g_gleak, const float* __restrict__ g_vleak,
                 const float* __restrict__ g_cm,
                 const float* __restrict__ g_ow, const float* __restrict__ g_ob,
                 float* __restrict__ outs)
{
    __shared__ float vb[128];
    __shared__ float sp_s[768], sq_s[768], ss_s[768];
    __shared__ float cmt_s[128], gl_s[128], glvl_s[128];
    __shared__ float ow_s[64], ob_s[64];

    const int tid = threadIdx.x;
    const int j_slot = tid >> 2;
    const int q = tid & 3;
    const int jj = meta_g[128 + j_slot];
    const int cnt = meta_g[jj];
    const int kq_lane = (cnt + 3 - q) >> 2;

    if (tid < 128) vb[tid] = 0.f;
    for (int idx = tid; idx < 768; idx += 512) {
        sp_s[idx] = g_sp[idx]; sq_s[idx] = g_sq[idx]; ss_s[idx] = g_ss[idx];
    }
    if (tid < 128) {
        cmt_s[tid] = log1pf(expf(g_cm[tid])) * 6.0f;
        float gl = log1pf(expf(g_gleak[tid]));
        gl_s[tid] = gl;
        glvl_s[tid] = gl * g_vleak[tid];
    }
    if (tid < 64) { ow_s[tid] = g_ow[tid]; ob_s[tid] = g_ob[tid]; }

    // entries -> named registers (zero-padded), then pin so the compiler
    // CANNOT rematerialize the loads inside the loop.
    const float4* eg = ent_g + (((jj << 2) + q) << 4);
#define ENT_LOAD(K) float4 e##K = eg[K];
    ENT_LOAD(0)  ENT_LOAD(1)  ENT_LOAD(2)  ENT_LOAD(3)
    ENT_LOAD(4)  ENT_LOAD(5)  ENT_LOAD(6)  ENT_LOAD(7)
    ENT_LOAD(8)  ENT_LOAD(9)  ENT_LOAD(10) ENT_LOAD(11)
    ENT_LOAD(12) ENT_LOAD(13) ENT_LOAD(14) ENT_LOAD(15)
#define ENT_PIN(K) asm volatile("" : "+v"(e##K.x), "+v"(e##K.y), "+v"(e##K.z), "+v"(e##K.w));
    ENT_PIN(0)  ENT_PIN(1)  ENT_PIN(2)  ENT_PIN(3)
    ENT_PIN(4)  ENT_PIN(5)  ENT_PIN(6)  ENT_PIN(7)
    ENT_PIN(8)  ENT_PIN(9)  ENT_PIN(10) ENT_PIN(11)
    ENT_PIN(12) ENT_PIN(13) ENT_PIN(14) ENT_PIN(15)

    // wave-uniform trip count
    int kqm = kq_lane;
#pragma unroll
    for (int m = 1; m < 64; m <<= 1) kqm = max(kqm, __shfl_xor(kqm, m));
    kqm = __builtin_amdgcn_readfirstlane(kqm);

    __syncthreads();

    const float cmt = cmt_s[jj], glf = gl_s[jj], glvl = glvl_s[jj];
    const float osc = (jj < 64) ? ow_s[jj] : 0.f;
    const float obi = (jj < 64) ? ob_s[jj] : 0.f;
    const int bg = blockIdx.x;
    const float* iprow = inp + bg * 576;
    float* orow = outs + ((bg * 96) << 6) + jj;
    float vcur = 0.f;
    const char* vbc = (const char*)vb;

#define ENT_DO(K) if (kqm > K) { \
        float v = *(const float*)(vbc + __float_as_int(e##K.w)); \
        float z = fmaf(e##K.x, v, e##K.y); \
        float r = __builtin_amdgcn_rcpf(1.0f + __builtin_amdgcn_exp2f(z)); \
        n = fmaf(e##K.z, r, n); \
        d = fmaf(fabsf(e##K.z), r, d); }

    for (int t = 0; t < 96; ++t) {
        // sensory: q handles k=q (all) and k=q+4 (q<2) -> covers k=0..5
        float sn, sd;
        {
            const int k1 = q;
            float z = fmaf(sp_s[(k1 << 7) + jj], iprow[k1], sq_s[(k1 << 7) + jj]);
            float r = __builtin_amdgcn_rcpf(1.0f + __builtin_amdgcn_exp2f(z));
            float sv = ss_s[(k1 << 7) + jj];
            sn = sv * r;
            sd = fabsf(sv) * r;
            if (q < 2) {
                const int k2 = q + 4;
                float z2 = fmaf(sp_s[(k2 << 7) + jj], iprow[k2], sq_s[(k2 << 7) + jj]);
                float r2 = __builtin_amdgcn_rcpf(1.0f + __builtin_amdgcn_exp2f(z2));
                float sv2 = ss_s[(k2 << 7) + jj];
                sn = fmaf(sv2, r2, sn);
                sd = fmaf(fabsf(sv2), r2, sd);
            }
        }
        sn += __shfl_xor(sn, 1); sd += __shfl_xor(sd, 1);
        sn += __shfl_xor(sn, 2); sd += __shfl_xor(sd, 2);
        iprow += 6;

        for (int u = 0; u < 6; ++u) {
            float n = 0.f, d = 0.f;
            ENT_DO(0)  ENT_DO(1)  ENT_DO(2)  ENT_DO(3)
            ENT_DO(4)  ENT_DO(5)  ENT_DO(6)  ENT_DO(7)
            ENT_DO(8)  ENT_DO(9)  ENT_DO(10) ENT_DO(11)
            ENT_DO(12) ENT_DO(13) ENT_DO(14) ENT_DO(15)
            n += __shfl_xor(n, 1); d += __shfl_xor(d, 1);
            n += __shfl_xor(n, 2); d += __shfl_xor(d, 2);
            __syncthreads();   // all vb reads done before update writes
            float num = fmaf(cmt, vcur, glvl) + n + sn;
            float den = cmt + glf + d + sd;
            vcur = num / (den + 1e-8f);
            if (q == 0) {
                vb[jj] = vcur;
                if (u == 5 && jj < 64) orow[0] = fmaf(vcur, osc, obi);
            }
            __syncthreads();   // updates visible to next unfold
        }
        orow += 64;
    }
}

// ---------------------------------------------------------------------------
// attention pooling over T + classifier, one block per batch element.
// ---------------------------------------------------------------------------
__global__ __launch_bounds__(128)
void lnn_attn(const float* __restrict__ outs,
              const float* __restrict__ aw1, const float* __restrict__ ab1,
              const float* __restrict__ aw2,
              const float* __restrict__ cw1, const float* __restrict__ cb1,
              const float* __restrict__ cw2, const float* __restrict__ cb2,
              float* __restrict__ out)
{
    __shared__ float o_s[96 * 65];
    __shared__ float aw1_s[64 * 32];
    __shared__ float scr[96], attw[96], ctx_s[64], h2_s[128];

    const int b = blockIdx.x, tid = threadIdx.x;
    const float* ob = outs + b * 6144;
    for (int idx = tid; idx < 6144; idx += 128)
        o_s[(idx >> 6) * 65 + (idx & 63)] = ob[idx];
    for (int idx = tid; idx < 2048; idx += 128)
        aw1_s[idx] = aw1[idx];
    __syncthreads();

    if (tid < 96) {
        float h1[32];
#pragma unroll
        for (int m = 0; m < 32; ++m) h1[m] = ab1[m];
        for (int jj = 0; jj < 64; ++jj) {
            float ov = o_s[tid * 65 + jj];
#pragma unroll
            for (int m = 0; m < 32; ++m) h1[m] = fmaf(ov, aw1_s[(jj << 5) + m], h1[m]);
        }
        float sc = 0.f;
#pragma unroll
        for (int m = 0; m < 32; ++m) sc = fmaf(fmaxf(h1[m], 0.f), aw2[m], sc);
        scr[tid] = sc;
    }
    __syncthreads();

    float mx = -1e30f;
    for (int k = 0; k < 96; ++k) mx = fmaxf(mx, scr[k]);
    float sum = 0.f;
    for (int k = 0; k < 96; ++k) sum += expf(scr[k] - mx);
    if (tid < 96) attw[tid] = expf(scr[tid] - mx) / sum;
    __syncthreads();

    if (tid < 64) {
        float c = 0.f;
        for (int k = 0; k < 96; ++k) c = fmaf(attw[k], o_s[k * 65 + tid], c);
        ctx_s[tid] = c;
    }
    __syncthreads();

    {
        float a = cb1[tid];
        for (int jj = 0; jj < 64; ++jj) a = fmaf(ctx_s[jj], cw1[(jj << 7) + tid], a);
        h2_s[tid] = fmaxf(a, 0.f);
    }
    __syncthreads();

    if (tid < 100) {
        float a = cb2[tid];
        for (int m = 0; m < 128; ++m) a = fmaf(h2_s[m], cw2[m * 100 + tid], a);
        out[b * 100 + tid] = a;
    }
}

// ---------------------------------------------------------------------------
extern "C" void kernel_launch(void* const* d_in, const int* in_sizes, int n_in,
                              void* d_out, int out_size, void* d_ws, size_t ws_size,
                              hipStream_t stream)
{
    const float* x     = (const float*)d_in[0];
    const float* ln_g  = (const float*)d_in[1];
    const float* ln_b  = (const float*)d_in[2];
    const float* gleak = (const float*)d_in[3];
    const float* vleak = (const float*)d_in[4];
    const float* cm    = (const float*)d_in[5];
    const float* sigma = (const float*)d_in[6];
    const float* mu    = (const float*)d_in[7];
    const float* w     = (const float*)d_in[8];
    const float* erev  = (const float*)d_in[9];
    const float* ssig  = (const float*)d_in[10];
    const float* smu   = (const float*)d_in[11];
    const float* sw    = (const float*)d_in[12];
    const float* serev = (const float*)d_in[13];
    const float* in_w  = (const float*)d_in[14];
    const float* in_b  = (const float*)d_in[15];
    const float* ow    = (const float*)d_in[16];
    const float* obb   = (const float*)d_in[17];
    const float* aw1   = (const float*)d_in[18];
    const float* ab1   = (const float*)d_in[19];
    const float* aw2   = (const float*)d_in[20];
    const float* cw1   = (const float*)d_in[21];
    const float* cb1   = (const float*)d_in[22];
    const float* cw2   = (const float*)d_in[23];
    const float* cb2   = (const float*)d_in[24];
    const float* mask  = (const float*)d_in[25];
    const float* smask = (const float*)d_in[26];

    float* ws = (float*)d_ws;
    float*  inp   = ws;                          // 589824 f
    float*  sp    = ws + 589824;                 // 768
    float*  sq    = ws + 590592;                 // 768
    float*  ss    = ws + 591360;                 // 768
    float4* ent_g = (float4*)(ws + 592128);      // 128*64 float4 = 32768 f (16B aligned)
    int*    meta  = (int*)(ws + 624896);         // 256 ints (pad 512)
    float*  outs  = ws + 625408;                 // 6291456 f

    lnn_prep_csc<<<1, 128, 0, stream>>>(sigma, mu, w, erev, mask, ent_g, meta);
    lnn_prep_sens<<<1, 768, 0, stream>>>(ssig, smu, sw, serev, smask, sp, sq, ss);
    lnn_prep2<<<384, 256, 0, stream>>>(x, ln_g, ln_b, in_w, in_b, inp);
    lnn_main_sp<<<1024, 512, 0, stream>>>(inp, ent_g, meta, sp, sq, ss,
                                          gleak, vleak, cm, ow, obb, outs);
    lnn_attn<<<1024, 128, 0, stream>>>(outs, aw1, ab1, aw2, cw1, cb1, cw2, cb2,
                                       (float*)d_out);
}

// Round 10
// 1258.208 us; speedup vs baseline: 5.2759x; 1.1762x over previous
//
#include <hip/hip_runtime.h>
#include <math.h>

#define LOG2E 1.4426950408889634f
#define KQ 16   // max entries per column-quarter (column nnz <= 64)

// ---------------------------------------------------------------------------
// prep_csc: fixed-stride padded CSC [col][quarter(4)][KQ] of recurrent synapses.
// entry {p=-sigma*log2e, q=sigma*mu*log2e, s=softplus(w)*erev, w=i*4 (byte off)}.
// Zero-padded (p=q=s=0 -> s*sigmoid(0)=0: exact no-op, also under pair-rcp).
// Column c-th nonzero -> quarter c&3. Within a quarter, entries sorted by
// ((i&31) - lane_slot)&31 so step-k banks across the wave rotate near-perfectly.
// meta: [0..127]=cnt by col, [128..255]=perm (rank-sorted desc by cnt).
// ---------------------------------------------------------------------------
__global__ __launch_bounds__(128)
void lnn_prep_csc(const float* __restrict__ sigma, const float* __restrict__ mu,
                  const float* __restrict__ w, const float* __restrict__ erev,
                  const float* __restrict__ mask,
                  float4* __restrict__ ent_g, int* __restrict__ meta_g)
{
    __shared__ int cnt_s[128], rank_s[128];
    const int j = threadIdx.x;
    int cnt = 0;
    for (int i = 0; i < 128; ++i) cnt += (mask[i * 128 + j] != 0.0f) ? 1 : 0;
    cnt_s[j] = cnt;
    __syncthreads();
    int rank = 0;
    for (int i = 0; i < 128; ++i) {
        int ci = cnt_s[i];
        rank += (ci > cnt || (ci == cnt && i < j)) ? 1 : 0;
    }
    meta_g[j] = cnt;
    meta_g[128 + rank] = j;
    rank_s[j] = rank;
    __syncthreads();
    const int slotbase = (rank_s[j] & 15) * 4;

    float4 z; z.x = 0.f; z.y = 0.f; z.z = 0.f; z.w = __int_as_float(0);
    for (int c = 0; c < 64; ++c) ent_g[(j << 6) + c] = z;

    for (int q = 0; q < 4; ++q) {
        int idxs[KQ];
        int m = 0, c = 0;
        for (int i = 0; i < 128; ++i) {
            if (mask[i * 128 + j] != 0.0f) {
                if ((c & 3) == q && m < KQ) idxs[m++] = i;
                ++c;
            }
        }
        const int slot = (slotbase + q) & 31;
        for (int a = 1; a < m; ++a) {            // insertion sort by bank key
            int v = idxs[a];
            int kv = ((v & 31) - slot) & 31;
            int bp = a;
            while (bp > 0) {
                int u = idxs[bp - 1];
                if ((((u & 31) - slot) & 31) <= kv) break;
                idxs[bp] = u; --bp;
            }
            idxs[bp] = v;
        }
        for (int k = 0; k < m; ++k) {
            int i = idxs[k];
            int gi = i * 128 + j;
            float sg = sigma[gi], mm = mu[gi];
            float4 e;
            e.x = -sg * LOG2E;
            e.y = sg * mm * LOG2E;
            e.z = log1pf(expf(w[gi])) * erev[gi];
            e.w = __int_as_float(i << 2);        // byte offset into vb row
            ent_g[(j << 6) + (q << 4) + k] = e;
        }
    }
}

// ---------------------------------------------------------------------------
// prep_sens: sensory synapse constants (6x128).
// ---------------------------------------------------------------------------
__global__ __launch_bounds__(768)
void lnn_prep_sens(const float* __restrict__ ssig, const float* __restrict__ smu,
                   const float* __restrict__ sw, const float* __restrict__ serev,
                   const float* __restrict__ smask,
                   float* __restrict__ g_sp, float* __restrict__ g_sq,
                   float* __restrict__ g_ss)
{
    int idx = threadIdx.x;
    float sg = ssig[idx], m = smu[idx];
    g_sp[idx] = -sg * LOG2E;
    g_sq[idx] = sg * m * LOG2E;
    g_ss[idx] = log1pf(expf(sw[idx])) * smask[idx] * serev[idx];
}

// ---------------------------------------------------------------------------
// prep2: LayerNorm(6) + input affine folded -> inp [B*T][6].
// ---------------------------------------------------------------------------
__global__ void lnn_prep2(const float* __restrict__ x,
                          const float* __restrict__ ln_g, const float* __restrict__ ln_b,
                          const float* __restrict__ in_w, const float* __restrict__ in_b,
                          float* __restrict__ inp)
{
    int r = blockIdx.x * 256 + threadIdx.x;
    if (r >= 1024 * 96) return;
    const float* xp = x + r * 6;
    float v[6];
#pragma unroll
    for (int k = 0; k < 6; ++k) v[k] = xp[k];
    float m = (v[0] + v[1] + v[2] + v[3] + v[4] + v[5]) * (1.0f / 6.0f);
    float var = 0.f;
#pragma unroll
    for (int k = 0; k < 6; ++k) { float d = v[k] - m; var = fmaf(d, d, var); }
    var *= (1.0f / 6.0f);
    float rs = rsqrtf(var + 1e-5f);
    float* op = inp + r * 6;
#pragma unroll
    for (int k = 0; k < 6; ++k)
        op[k] = fmaf(fmaf((v[k] - m) * rs, ln_g[k], ln_b[k]), in_w[k], in_b[k]);
}

// ---------------------------------------------------------------------------
// main (sparse, reg-entries, dbuf, pair-rcp): 1024 blocks x 512 threads.
// thread: j_slot = tid>>2 (rank), q = tid&3 (quarter). jj = perm[j_slot].
// Entries in 16 NAMED float4s pinned via opaque asm (R8: remat -> 19GB HBM).
// vb double-buffered [2][128] -> ONE barrier per unfold (R9: 2 barriers were
// part of the 42% non-VALU time). Buffer parity = wave-uniform branch so the
// offset folds into the ds_read immediate. Pair-rcp: one v_rcp per 2 entries.
// ---------------------------------------------------------------------------
__global__ __launch_bounds__(512, 4)
void lnn_main_sp(const float* __restrict__ inp, const float4* __restrict__ ent_g,
                 const int* __restrict__ meta_g,
                 const float* __restrict__ g_sp, const float* __restrict__ g_sq,
                 const float* __restrict__ g_ss,
                 const float* __restrict__ g_gleak, const float* __restrict__ g_vleak,
                 const float* __restrict__ g_cm,
                 const float* __restrict__ g_ow, const float* __restrict__ g_ob,
                 float* __restrict__ outs)
{
    __shared__ float vb[2][128];
    __shared__ float sp_s[768], sq_s[768], ss_s[768];
    __shared__ float cmt_s[128], gl_s[128], glvl_s[128];
    __shared__ float ow_s[64], ob_s[64];

    const int tid = threadIdx.x;
    const int j_slot = tid >> 2;
    const int q = tid & 3;
    const int jj = meta_g[128 + j_slot];
    const int cnt = meta_g[jj];
    const int kq_lane = (cnt + 3 - q) >> 2;

    if (tid < 256) ((float*)vb)[tid] = 0.f;
    for (int idx = tid; idx < 768; idx += 512) {
        sp_s[idx] = g_sp[idx]; sq_s[idx] = g_sq[idx]; ss_s[idx] = g_ss[idx];
    }
    if (tid < 128) {
        cmt_s[tid] = log1pf(expf(g_cm[tid])) * 6.0f;
        float gl = log1pf(expf(g_gleak[tid]));
        gl_s[tid] = gl;
        glvl_s[tid] = gl * g_vleak[tid];
    }
    if (tid < 64) { ow_s[tid] = g_ow[tid]; ob_s[tid] = g_ob[tid]; }

    // entries -> named registers (zero-padded), pinned against remat.
    const float4* eg = ent_g + (((jj << 2) + q) << 4);
#define ENT_LOAD(K) float4 e##K = eg[K];
    ENT_LOAD(0)  ENT_LOAD(1)  ENT_LOAD(2)  ENT_LOAD(3)
    ENT_LOAD(4)  ENT_LOAD(5)  ENT_LOAD(6)  ENT_LOAD(7)
    ENT_LOAD(8)  ENT_LOAD(9)  ENT_LOAD(10) ENT_LOAD(11)
    ENT_LOAD(12) ENT_LOAD(13) ENT_LOAD(14) ENT_LOAD(15)
#define ENT_PIN(K) asm volatile("" : "+v"(e##K.x), "+v"(e##K.y), "+v"(e##K.z), "+v"(e##K.w));
    ENT_PIN(0)  ENT_PIN(1)  ENT_PIN(2)  ENT_PIN(3)
    ENT_PIN(4)  ENT_PIN(5)  ENT_PIN(6)  ENT_PIN(7)
    ENT_PIN(8)  ENT_PIN(9)  ENT_PIN(10) ENT_PIN(11)
    ENT_PIN(12) ENT_PIN(13) ENT_PIN(14) ENT_PIN(15)

    // wave-uniform pair trip count
    int kqm = kq_lane;
#pragma unroll
    for (int m = 1; m < 64; m <<= 1) kqm = max(kqm, __shfl_xor(kqm, m));
    const int kqp = __builtin_amdgcn_readfirstlane((kqm + 1) >> 1);

    __syncthreads();

    const float cmt = cmt_s[jj], glf = gl_s[jj], glvl = glvl_s[jj];
    const float osc = (jj < 64) ? ow_s[jj] : 0.f;
    const float obi = (jj < 64) ? ob_s[jj] : 0.f;
    const int bg = blockIdx.x;
    const float* iprow = inp + bg * 576;
    float* orow = outs + ((bg * 96) << 6) + jj;
    float vcur = 0.f;
    const char* vbc = (const char*)&vb[0][0];

    // pair-rcp: sigma for entries KA,KB with one rcp. Zero-padded entries are
    // exact no-ops (a=1 -> partner's sigma unchanged, s=0 contributes 0).
#define ENT_DO2(P, KA, KB, OFS) if (kqp > P) { \
        float vA = *(const float*)(vbc + (OFS) + __float_as_int(e##KA.w)); \
        float vB = *(const float*)(vbc + (OFS) + __float_as_int(e##KB.w)); \
        float zA = fmaf(e##KA.x, vA, e##KA.y); \
        float zB = fmaf(e##KB.x, vB, e##KB.y); \
        float A = 1.0f + __builtin_amdgcn_exp2f(zA); \
        float B = 1.0f + __builtin_amdgcn_exp2f(zB); \
        float rP = __builtin_amdgcn_rcpf(A * B); \
        float sA = B * rP; \
        float sB = A * rP; \
        n = fmaf(e##KA.z, sA, n); d = fmaf(fabsf(e##KA.z), sA, d); \
        n = fmaf(e##KB.z, sB, n); d = fmaf(fabsf(e##KB.z), sB, d); }

#define ENT_BLOCK(OFS) \
        ENT_DO2(0, 0, 1, OFS)  ENT_DO2(1, 2, 3, OFS) \
        ENT_DO2(2, 4, 5, OFS)  ENT_DO2(3, 6, 7, OFS) \
        ENT_DO2(4, 8, 9, OFS)  ENT_DO2(5, 10, 11, OFS) \
        ENT_DO2(6, 12, 13, OFS) ENT_DO2(7, 14, 15, OFS)

    for (int t = 0; t < 96; ++t) {
        // sensory: q handles k=q (all) and k=q+4 (q<2) -> covers k=0..5
        float sn, sd;
        {
            const int k1 = q;
            float z = fmaf(sp_s[(k1 << 7) + jj], iprow[k1], sq_s[(k1 << 7) + jj]);
            float r = __builtin_amdgcn_rcpf(1.0f + __builtin_amdgcn_exp2f(z));
            float sv = ss_s[(k1 << 7) + jj];
            sn = sv * r;
            sd = fabsf(sv) * r;
            if (q < 2) {
                const int k2 = q + 4;
                float z2 = fmaf(sp_s[(k2 << 7) + jj], iprow[k2], sq_s[(k2 << 7) + jj]);
                float r2 = __builtin_amdgcn_rcpf(1.0f + __builtin_amdgcn_exp2f(z2));
                float sv2 = ss_s[(k2 << 7) + jj];
                sn = fmaf(sv2, r2, sn);
                sd = fmaf(fabsf(sv2), r2, sd);
            }
        }
        sn += __shfl_xor(sn, 1); sd += __shfl_xor(sd, 1);
        sn += __shfl_xor(sn, 2); sd += __shfl_xor(sd, 2);
        iprow += 6;

        // 6 unfolds; u even: read buf0 write buf1; u odd: read buf1 write buf0.
        for (int u = 0; u < 6; ++u) {
            float n = 0.f, d = 0.f;
            if (u & 1) { ENT_BLOCK(512) } else { ENT_BLOCK(0) }
            n += __shfl_xor(n, 1); d += __shfl_xor(d, 1);
            n += __shfl_xor(n, 2); d += __shfl_xor(d, 2);
            float num = fmaf(cmt, vcur, glvl) + n + sn;
            float den = cmt + glf + d + sd;
            vcur = num * __builtin_amdgcn_rcpf(den + 1e-8f);
            if (q == 0) {
                vb[(u & 1) ^ 1][jj] = vcur;
                if (u == 5 && jj < 64) orow[0] = fmaf(vcur, osc, obi);
            }
            __syncthreads();   // single barrier: writes visible, old-buf reads done
        }
        orow += 64;
    }
}

// ---------------------------------------------------------------------------
// attention pooling over T + classifier, one block per batch element.
// ---------------------------------------------------------------------------
__global__ __launch_bounds__(128)
void lnn_attn(const float* __restrict__ outs,
              const float* __restrict__ aw1, const float* __restrict__ ab1,
              const float* __restrict__ aw2,
              const float* __restrict__ cw1, const float* __restrict__ cb1,
              const float* __restrict__ cw2, const float* __restrict__ cb2,
              float* __restrict__ out)
{
    __shared__ float o_s[96 * 65];
    __shared__ float aw1_s[64 * 32];
    __shared__ float scr[96], attw[96], ctx_s[64], h2_s[128];

    const int b = blockIdx.x, tid = threadIdx.x;
    const float* ob = outs + b * 6144;
    for (int idx = tid; idx < 6144; idx += 128)
        o_s[(idx >> 6) * 65 + (idx & 63)] = ob[idx];
    for (int idx = tid; idx < 2048; idx += 128)
        aw1_s[idx] = aw1[idx];
    __syncthreads();

    if (tid < 96) {
        float h1[32];
#pragma unroll
        for (int m = 0; m < 32; ++m) h1[m] = ab1[m];
        for (int jj = 0; jj < 64; ++jj) {
            float ov = o_s[tid * 65 + jj];
#pragma unroll
            for (int m = 0; m < 32; ++m) h1[m] = fmaf(ov, aw1_s[(jj << 5) + m], h1[m]);
        }
        float sc = 0.f;
#pragma unroll
        for (int m = 0; m < 32; ++m) sc = fmaf(fmaxf(h1[m], 0.f), aw2[m], sc);
        scr[tid] = sc;
    }
    __syncthreads();

    float mx = -1e30f;
    for (int k = 0; k < 96; ++k) mx = fmaxf(mx, scr[k]);
    float sum = 0.f;
    for (int k = 0; k < 96; ++k) sum += expf(scr[k] - mx);
    if (tid < 96) attw[tid] = expf(scr[tid] - mx) / sum;
    __syncthreads();

    if (tid < 64) {
        float c = 0.f;
        for (int k = 0; k < 96; ++k) c = fmaf(attw[k], o_s[k * 65 + tid], c);
        ctx_s[tid] = c;
    }
    __syncthreads();

    {
        float a = cb1[tid];
        for (int jj = 0; jj < 64; ++jj) a = fmaf(ctx_s[jj], cw1[(jj << 7) + tid], a);
        h2_s[tid] = fmaxf(a, 0.f);
    }
    __syncthreads();

    if (tid < 100) {
        float a = cb2[tid];
        for (int m = 0; m < 128; ++m) a = fmaf(h2_s[m], cw2[m * 100 + tid], a);
        out[b * 100 + tid] = a;
    }
}

// ---------------------------------------------------------------------------
extern "C" void kernel_launch(void* const* d_in, const int* in_sizes, int n_in,
                              void* d_out, int out_size, void* d_ws, size_t ws_size,
                              hipStream_t stream)
{
    const float* x     = (const float*)d_in[0];
    const float* ln_g  = (const float*)d_in[1];
    const float* ln_b  = (const float*)d_in[2];
    const float* gleak = (const float*)d_in[3];
    const float* vleak = (const float*)d_in[4];
    const float* cm    = (const float*)d_in[5];
    const float* sigma = (const float*)d_in[6];
    const float* mu    = (const float*)d_in[7];
    const float* w     = (const float*)d_in[8];
    const float* erev  = (const float*)d_in[9];
    const float* ssig  = (const float*)d_in[10];
    const float* smu   = (const float*)d_in[11];
    const float* sw    = (const float*)d_in[12];
    const float* serev = (const float*)d_in[13];
    const float* in_w  = (const float*)d_in[14];
    const float* in_b  = (const float*)d_in[15];
    const float* ow    = (const float*)d_in[16];
    const float* obb   = (const float*)d_in[17];
    const float* aw1   = (const float*)d_in[18];
    const float* ab1   = (const float*)d_in[19];
    const float* aw2   = (const float*)d_in[20];
    const float* cw1   = (const float*)d_in[21];
    const float* cb1   = (const float*)d_in[22];
    const float* cw2   = (const float*)d_in[23];
    const float* cb2   = (const float*)d_in[24];
    const float* mask  = (const float*)d_in[25];
    const float* smask = (const float*)d_in[26];

    float* ws = (float*)d_ws;
    float*  inp   = ws;                          // 589824 f
    float*  sp    = ws + 589824;                 // 768
    float*  sq    = ws + 590592;                 // 768
    float*  ss    = ws + 591360;                 // 768
    float4* ent_g = (float4*)(ws + 592128);      // 128*64 float4 = 32768 f (16B aligned)
    int*    meta  = (int*)(ws + 624896);         // 256 ints (pad 512)
    float*  outs  = ws + 625408;                 // 6291456 f

    lnn_prep_csc<<<1, 128, 0, stream>>>(sigma, mu, w, erev, mask, ent_g, meta);
    lnn_prep_sens<<<1, 768, 0, stream>>>(ssig, smu, sw, serev, smask, sp, sq, ss);
    lnn_prep2<<<384, 256, 0, stream>>>(x, ln_g, ln_b, in_w, in_b, inp);
    lnn_main_sp<<<1024, 512, 0, stream>>>(inp, ent_g, meta, sp, sq, ss,
                                          gleak, vleak, cm, ow, obb, outs);
    lnn_attn<<<1024, 128, 0, stream>>>(outs, aw1, ab1, aw2, cw1, cb1, cw2, cb2,
                                       (float*)d_out);
}